// Round 14
// baseline (238.426 us; speedup 1.0000x reference)
//
#include <hip/hip_runtime.h>

#define BB     2048
#define TT     512
#define INDIM  28
#define HH     64
#define NC     10
#define ROWS   16
#define NTHREADS 512   // 8 waves: waves w,w+4 duplicate MFMAs for unit-group w&3, split gate VALU
#define LDH    104     // halfs per H row: 208 B stride -> 16B-aligned rows, 2-way-max banking (free)

typedef __attribute__((ext_vector_type(8))) _Float16 f16x8;
typedef __attribute__((ext_vector_type(2))) _Float16 f16x2;
typedef __attribute__((ext_vector_type(2))) __fp16   fp16x2;   // native cvt_pkrtz result type
typedef __attribute__((ext_vector_type(4))) float     f32x4;

__device__ __forceinline__ float frcp(float v)  { return __builtin_amdgcn_rcpf(v); }
__device__ __forceinline__ float fsig(float v)  { return frcp(1.f + __expf(-v)); }
__device__ __forceinline__ float ftanh_(float v){ return fmaf(-2.f, frcp(1.f + __expf(2.f*v)), 1.f); }

#define MFMA(A_, B_, C_) __builtin_amdgcn_mfma_f32_16x16x32_f16((A_), (B_), (C_), 0, 0, 0)

// LDS-only barrier: orders our ds_writes (lgkmcnt(0)) then syncs. Does NOT drain vmcnt,
// so the raw-float4 x-ring global loads stay in flight across step boundaries.
__device__ __forceinline__ void lds_barrier() {
    asm volatile("s_waitcnt lgkmcnt(0)" ::: "memory");
    __builtin_amdgcn_s_barrier();
}

// ring slot -> f16x8 B-fragment via 4 packed cvt (v_cvt_pkrtz_f16_f32); register-only,
// scheduled before the barrier of the previous step. RTZ on x: preact error ~1e-5.
// union type-puns the builtin's __fp16x2 to _Float16x8 (identical bit layout).
__device__ __forceinline__ f16x8 cvt_x8(const float4 a, const float4 b) {
    union { fp16x2 p[4]; f16x8 v; } U;
    U.p[0] = __builtin_amdgcn_cvt_pkrtz(a.x, a.y);
    U.p[1] = __builtin_amdgcn_cvt_pkrtz(a.z, a.w);
    U.p[2] = __builtin_amdgcn_cvt_pkrtz(b.x, b.y);
    U.p[3] = __builtin_amdgcn_cvt_pkrtz(b.z, b.w);
    return U.v;
}

// r12 structure (operand-swapped pure-fp16, D = W·[h|x]^T, 16 rows/block) at 8 waves:
// waves w and w+4 compute IDENTICAL 9-MFMA accumulators for unit-group w&3 (MFMA pipe
// has 8x headroom; duplication is free), then SPLIT the serial gate VALU: wave w does
// C-regs {0,1}, wave w+4 regs {2,3}, each ds_write_b32's its own f16x2. Per-wave
// post-MFMA chain halves and 2 waves/SIMD fill each other's ds/trans/MFMA latency.
// h trajectory is bit-identical to r12 (duplicated MFMAs deterministic).
extern "C" __global__ __launch_bounds__(NTHREADS, 2)
void gru_mfma(const float* __restrict__ x,
              const float* __restrict__ W_ih,
              const float* __restrict__ W_hh,
              const float* __restrict__ b_ih,
              const float* __restrict__ b_hh,
              const float* __restrict__ W_out,
              const float* __restrict__ b_out,
              float* __restrict__ out)
{
    __shared__ __align__(16) _Float16 H_[2][16][LDH];
    __shared__ float hs_f[ROWS][HH];
    __shared__ float lg[ROWS][NC];

    const int tid  = threadIdx.x;
    const int wave = tid >> 6;
    const int wq   = wave & 3;        // unit group (same as r12's w)
    const int half = wave >> 2;       // 0: gate-regs 0,1  1: gate-regs 2,3
    const int l    = tid & 63;
    const int c    = l & 15;          // batch row this lane owns / B col / A row
    const int hi   = l >> 4;          // k-slice for frags, unit-group for C
    const int hi8  = hi * 8;
    const int u    = wq * 16 + c;     // unit index for the weight A-frags
    const int u0   = wq * 16 + 4 * hi;// first unit of this lane's 4 C regs
    const int r0   = blockIdx.x * ROWS;

    // ---- weight fragments (A-operand), fp16, register-resident ----
    // frag f -> (gate g, kstep s): 0..2:(r,s) 3..5:(z,s) 6..7:(nh,0/1) 8:(nx,2)
    f16x8 Bh[9];
    {
        const int GS[9][2] = {{0,0},{0,1},{0,2},{1,0},{1,1},{1,2},{2,0},{2,1},{3,2}};
        #pragma unroll
        for (int f = 0; f < 9; ++f) {
            const int g = GS[f][0], s = GS[f][1];
            #pragma unroll
            for (int j = 0; j < 8; ++j) {
                const int k = s * 32 + hi8 + j;
                float v = 0.f;
                if (g == 2)      { if (k < 64) v = W_hh[(size_t)(u + 128) * HH + k]; }
                else if (g == 3) { if (k >= 64 && k < 64 + INDIM) v = W_ih[(size_t)(u + 128) * INDIM + (k - 64)]; }
                else {
                    const int ru = u + 64 * g;
                    if (k < 64)              v = W_hh[(size_t)ru * HH + k];
                    else if (k < 64 + INDIM) v = W_ih[(size_t)ru * INDIM + (k - 64)];
                }
                Bh[f][j] = (_Float16)v;
            }
        }
    }
    // bias vectors as accumulator inits: elem i <-> unit u0+i
    f32x4 bv_r, bv_z, bv_nh, bv_nx;
    #pragma unroll
    for (int i = 0; i < 4; ++i) {
        bv_r[i]  = b_ih[u0 + i]       + b_hh[u0 + i];
        bv_z[i]  = b_ih[u0 + i + 64]  + b_hh[u0 + i + 64];
        bv_nh[i] = b_hh[u0 + i + 128];
        bv_nx[i] = b_ih[u0 + i + 128];
    }

    // ---- zero both H buffers (h starts at 0) ----
    for (int i = tid; i < 2 * 16 * LDH; i += NTHREADS) ((_Float16*)H_)[i] = (_Float16)0.f;

    // ---- x ring (raw float4, 8 deep): lane owns x[row c][dims hi8..+7] ----
    const float* xlane = x + (size_t)(r0 + c) * (size_t)TT * INDIM + hi8;
    const float4 zf4 = {0.f, 0.f, 0.f, 0.f};
    const bool xfull = (hi < 3);
    float4 xa[8], xb[8];                 // slot k holds x_{8g+k}; hi==3: dims 28..31 = 0
    #pragma unroll
    for (int k = 0; k < 8; ++k) {
        xa[k] = *(const float4*)(xlane + (size_t)k * INDIM);
        xb[k] = xfull ? *(const float4*)(xlane + (size_t)k * INDIM + 4) : zf4;
    }
    __syncthreads();

    float h0 = 0.f, h1 = 0.f;            // h for (row c, units u0+2*half, u0+2*half+1)
    f16x8 xf = cvt_x8(xa[0], xb[0]);     // step-0 x fragment, precomputed
    int p = 0;

    const float* xnext = xlane + (size_t)8 * INDIM;   // base of next group's reloads

    for (int g = 0; g < TT / 8; ++g) {
        const bool more = (g + 1) < (TT / 8);
        #pragma unroll
        for (int k = 0; k < 8; ++k) {
            // h B-frags: issue reads first (latency hides under the x-part MFMAs)
            const f16x8 bf0 = *(const f16x8*)&H_[p][c][hi8];
            const f16x8 bf1 = *(const f16x8*)&H_[p][c][32 + hi8];

            // x-part MFMAs (independent of the reads), bias-initialized
            f32x4 a0 = MFMA(Bh[2], xf, bv_r);
            f32x4 a1 = MFMA(Bh[5], xf, bv_z);
            f32x4 a3 = MFMA(Bh[8], xf, bv_nx);
            // h-part MFMAs
            f32x4 a2 = MFMA(Bh[6], bf0, bv_nh);
            a0 = MFMA(Bh[0], bf0, a0);
            a1 = MFMA(Bh[3], bf0, a1);
            a2 = MFMA(Bh[7], bf1, a2);
            a0 = MFMA(Bh[1], bf1, a0);
            a1 = MFMA(Bh[4], bf1, a1);

            // gate math for THIS wave's half only (wave-uniform branch, const indices)
            f16x2 hv;
            if (half == 0) {
                {   const float rg = fsig(a0[0]);
                    const float zg = fsig(a1[0]);
                    const float ng = ftanh_(fmaf(rg, a2[0], a3[0]));
                    h0 = fmaf(zg, h0 - ng, ng); hv[0] = (_Float16)h0; }
                {   const float rg = fsig(a0[1]);
                    const float zg = fsig(a1[1]);
                    const float ng = ftanh_(fmaf(rg, a2[1], a3[1]));
                    h1 = fmaf(zg, h1 - ng, ng); hv[1] = (_Float16)h1; }
            } else {
                {   const float rg = fsig(a0[2]);
                    const float zg = fsig(a1[2]);
                    const float ng = ftanh_(fmaf(rg, a2[2], a3[2]));
                    h0 = fmaf(zg, h0 - ng, ng); hv[0] = (_Float16)h0; }
                {   const float rg = fsig(a0[3]);
                    const float zg = fsig(a1[3]);
                    const float ng = ftanh_(fmaf(rg, a2[3], a3[3]));
                    h1 = fmaf(zg, h1 - ng, ng); hv[1] = (_Float16)h1; }
            }
            // ONE dword write: H[row c][units u0+2*half .. +1]
            *(f16x2*)&H_[p ^ 1][c][u0 + 2 * half] = hv;

            // reload ring slot k for step t+8 (raw float4; stays in flight across barriers)
            if (more) {
                xa[k] = *(const float4*)(xnext + (size_t)k * INDIM);
                if (xfull) xb[k] = *(const float4*)(xnext + (size_t)k * INDIM + 4);
            }
            // next step's x fragment: register-only cvt, BEFORE the barrier
            xf = cvt_x8(xa[(k + 1) & 7], xb[(k + 1) & 7]);

            lds_barrier();
            p ^= 1;
        }
        xnext += (size_t)8 * INDIM;
    }

    // ---- epilogue: logits + softmax for this block's 16 rows ----
    hs_f[c][u0 + 2 * half]     = h0;
    hs_f[c][u0 + 2 * half + 1] = h1;
    __syncthreads();
    if (tid < ROWS * NC) {
        const int rr = tid / NC, cc = tid % NC;
        float s = b_out[cc];
        const float* wo = W_out + (size_t)cc * HH;
        #pragma unroll
        for (int j = 0; j < HH; ++j) s = fmaf(wo[j], hs_f[rr][j], s);
        lg[rr][cc] = s;
    }
    __syncthreads();
    if (tid < ROWS) {
        float mx = -1e30f;
        #pragma unroll
        for (int cc = 0; cc < NC; ++cc) mx = fmaxf(mx, lg[tid][cc]);
        float e[NC]; float ssum = 0.f;
        #pragma unroll
        for (int cc = 0; cc < NC; ++cc) { e[cc] = __expf(lg[tid][cc] - mx); ssum += e[cc]; }
        const float inv = 1.f / ssum;
        float* op = out + (size_t)(r0 + tid) * NC;
        #pragma unroll
        for (int cc = 0; cc < NC; ++cc) op[cc] = e[cc] * inv;
    }
}

extern "C" void kernel_launch(void* const* d_in, const int* in_sizes, int n_in,
                              void* d_out, int out_size, void* d_ws, size_t ws_size,
                              hipStream_t stream) {
    const float* x     = (const float*)d_in[0];
    const float* W_ih  = (const float*)d_in[1];
    const float* W_hh  = (const float*)d_in[2];
    const float* b_ih  = (const float*)d_in[3];
    const float* b_hh  = (const float*)d_in[4];
    const float* W_out = (const float*)d_in[5];
    const float* b_out = (const float*)d_in[6];
    (void)in_sizes; (void)n_in; (void)d_ws; (void)ws_size; (void)out_size;

    gru_mfma<<<BB / ROWS, NTHREADS, 0, stream>>>(x, W_ih, W_hh, b_ih, b_hh,
                                                 W_out, b_out, (float*)d_out);
}

// Round 15
// 185.730 us; speedup vs baseline: 1.2837x; 1.2837x over previous
//
#include <hip/hip_runtime.h>

#define BB     2048
#define TT     512
#define INDIM  28
#define HH     64
#define NC     10
#define ROWS   16
#define NTHREADS 256
#define LDH    104   // halfs per H row: 208 B stride -> 16B-aligned rows, 2-way-max banking (free)

typedef __attribute__((ext_vector_type(8))) _Float16 f16x8;
typedef __attribute__((ext_vector_type(4))) _Float16 f16x4;
typedef __attribute__((ext_vector_type(4))) float     f32x4;

__device__ __forceinline__ float frcp(float v)  { return __builtin_amdgcn_rcpf(v); }
__device__ __forceinline__ float fsig(float v)  { return frcp(1.f + __expf(-v)); }
__device__ __forceinline__ float ftanh_(float v){ return fmaf(-2.f, frcp(1.f + __expf(2.f*v)), 1.f); }

#define MFMA(A_, B_, C_) __builtin_amdgcn_mfma_f32_16x16x32_f16((A_), (B_), (C_), 0, 0, 0)

// LDS-only barrier: orders our ds_writes (lgkmcnt(0)) then syncs. Does NOT drain vmcnt,
// so the raw-float4 x-ring global loads stay in flight across step boundaries.
__device__ __forceinline__ void lds_barrier() {
    asm volatile("s_waitcnt lgkmcnt(0)" ::: "memory");
    __builtin_amdgcn_s_barrier();
}

// convert a ring slot (raw float4 pair) to the f16x8 B-fragment — register-only
__device__ __forceinline__ f16x8 cvt_x8(const float4 a, const float4 b) {
    f16x8 r;
    r[0] = (_Float16)a.x; r[1] = (_Float16)a.y; r[2] = (_Float16)a.z; r[3] = (_Float16)a.w;
    r[4] = (_Float16)b.x; r[5] = (_Float16)b.y; r[6] = (_Float16)b.z; r[7] = (_Float16)b.w;
    return r;
}

// r12 (verified 187 us): operand-swapped pure-fp16, D = W·[h|x]^T, 16 rows/block,
// 4 waves, 8-deep raw-float4 x ring, LDS-only barrier, bias-in-C-init.
// Sole change vs r12: next step's xf cvt is computed BETWEEN the x-part MFMAs and the
// h-part MFMAs — register-only work placed inside the ds_read latency shadow.
extern "C" __global__ __launch_bounds__(NTHREADS, 1)
void gru_mfma(const float* __restrict__ x,
              const float* __restrict__ W_ih,
              const float* __restrict__ W_hh,
              const float* __restrict__ b_ih,
              const float* __restrict__ b_hh,
              const float* __restrict__ W_out,
              const float* __restrict__ b_out,
              float* __restrict__ out)
{
    __shared__ __align__(16) _Float16 H_[2][16][LDH];
    __shared__ float hs_f[ROWS][HH];
    __shared__ float lg[ROWS][NC];

    const int tid = threadIdx.x;
    const int w   = tid >> 6;
    const int l   = tid & 63;
    const int c   = l & 15;          // batch row this lane owns / B col / A row
    const int hi  = l >> 4;          // k-slice for frags, unit-group for C
    const int hi8 = hi * 8;
    const int u   = w * 16 + c;      // unit index for the weight A-frags
    const int u0  = w * 16 + 4 * hi; // first unit of this lane's 4 C regs
    const int r0  = blockIdx.x * ROWS;

    // ---- weight fragments (A-operand), fp16, register-resident ----
    // frag f -> (gate g, kstep s): 0..2:(r,s) 3..5:(z,s) 6..7:(nh,0/1) 8:(nx,2)
    f16x8 Bh[9];
    {
        const int GS[9][2] = {{0,0},{0,1},{0,2},{1,0},{1,1},{1,2},{2,0},{2,1},{3,2}};
        #pragma unroll
        for (int f = 0; f < 9; ++f) {
            const int g = GS[f][0], s = GS[f][1];
            #pragma unroll
            for (int j = 0; j < 8; ++j) {
                const int k = s * 32 + hi8 + j;
                float v = 0.f;
                if (g == 2)      { if (k < 64) v = W_hh[(size_t)(u + 128) * HH + k]; }
                else if (g == 3) { if (k >= 64 && k < 64 + INDIM) v = W_ih[(size_t)(u + 128) * INDIM + (k - 64)]; }
                else {
                    const int ru = u + 64 * g;
                    if (k < 64)              v = W_hh[(size_t)ru * HH + k];
                    else if (k < 64 + INDIM) v = W_ih[(size_t)ru * INDIM + (k - 64)];
                }
                Bh[f][j] = (_Float16)v;
            }
        }
    }
    // bias vectors as accumulator inits: elem i <-> unit u0+i
    f32x4 bv_r, bv_z, bv_nh, bv_nx;
    #pragma unroll
    for (int i = 0; i < 4; ++i) {
        bv_r[i]  = b_ih[u0 + i]       + b_hh[u0 + i];
        bv_z[i]  = b_ih[u0 + i + 64]  + b_hh[u0 + i + 64];
        bv_nh[i] = b_hh[u0 + i + 128];
        bv_nx[i] = b_ih[u0 + i + 128];
    }

    // ---- zero both H buffers (h starts at 0) ----
    for (int i = tid; i < 2 * 16 * LDH; i += NTHREADS) ((_Float16*)H_)[i] = (_Float16)0.f;

    // ---- x ring (raw float4, 8 deep): lane owns x[row c][dims hi8..+7] ----
    const float* xlane = x + (size_t)(r0 + c) * (size_t)TT * INDIM + hi8;
    const float4 zf4 = {0.f, 0.f, 0.f, 0.f};
    const bool xfull = (hi < 3);
    float4 xa[8], xb[8];                 // slot k holds x_{8g+k}; hi==3: dims 28..31 = 0
    #pragma unroll
    for (int k = 0; k < 8; ++k) {
        xa[k] = *(const float4*)(xlane + (size_t)k * INDIM);
        xb[k] = xfull ? *(const float4*)(xlane + (size_t)k * INDIM + 4) : zf4;
    }
    __syncthreads();

    float h[4] = {0.f, 0.f, 0.f, 0.f};   // h for (row c, units u0..u0+3)
    f16x8 xf = cvt_x8(xa[0], xb[0]);     // step-0 x fragment, precomputed
    int p = 0;

    const float* xnext = xlane + (size_t)8 * INDIM;   // base of next group's reloads

    for (int g = 0; g < TT / 8; ++g) {
        const bool more = (g + 1) < (TT / 8);
        #pragma unroll
        for (int k = 0; k < 8; ++k) {
            // h B-frags: issue reads first (latency hides under the x-part MFMAs + cvt)
            const f16x8 bf0 = *(const f16x8*)&H_[p][c][hi8];
            const f16x8 bf1 = *(const f16x8*)&H_[p][c][32 + hi8];

            // x-part MFMAs (independent of the reads), bias-initialized
            f32x4 a0 = MFMA(Bh[2], xf, bv_r);
            f32x4 a1 = MFMA(Bh[5], xf, bv_z);
            f32x4 a3 = MFMA(Bh[8], xf, bv_nx);

            // next step's x fragment: register-only cvt, INSIDE the ds_read shadow
            const f16x8 xf_next = cvt_x8(xa[(k + 1) & 7], xb[(k + 1) & 7]);

            // h-part MFMAs (compiler inserts the lgkmcnt right before first use)
            f32x4 a2 = MFMA(Bh[6], bf0, bv_nh);
            a0 = MFMA(Bh[0], bf0, a0);
            a1 = MFMA(Bh[3], bf0, a1);
            a2 = MFMA(Bh[7], bf1, a2);
            a0 = MFMA(Bh[1], bf1, a0);
            a1 = MFMA(Bh[4], bf1, a1);

            // gate math fully in-lane: elem i = unit u0+i, row c
            f16x4 hv;
            #pragma unroll
            for (int i = 0; i < 4; ++i) {
                const float rg = fsig(a0[i]);
                const float zg = fsig(a1[i]);
                const float ng = ftanh_(fmaf(rg, a2[i], a3[i]));
                h[i] = fmaf(zg, h[i] - ng, ng);      // (1-z)*n + z*h
                hv[i] = (_Float16)h[i];
            }
            // ONE packed write: H[row c][units u0..u0+3]
            *(f16x4*)&H_[p ^ 1][c][u0] = hv;

            // reload ring slot k for step t+8 (raw float4; stays in flight across barriers)
            if (more) {
                xa[k] = *(const float4*)(xnext + (size_t)k * INDIM);
                if (xfull) xb[k] = *(const float4*)(xnext + (size_t)k * INDIM + 4);
            }
            xf = xf_next;

            lds_barrier();
            p ^= 1;
        }
        xnext += (size_t)8 * INDIM;
    }

    // ---- epilogue: logits + softmax for this block's 16 rows ----
    #pragma unroll
    for (int i = 0; i < 4; ++i) hs_f[c][u0 + i] = h[i];
    __syncthreads();
    if (tid < ROWS * NC) {
        const int rr = tid / NC, cc = tid % NC;
        float s = b_out[cc];
        const float* wo = W_out + (size_t)cc * HH;
        #pragma unroll
        for (int j = 0; j < HH; ++j) s = fmaf(wo[j], hs_f[rr][j], s);
        lg[rr][cc] = s;
    }
    __syncthreads();
    if (tid < ROWS) {
        float mx = -1e30f;
        #pragma unroll
        for (int cc = 0; cc < NC; ++cc) mx = fmaxf(mx, lg[tid][cc]);
        float e[NC]; float ssum = 0.f;
        #pragma unroll
        for (int cc = 0; cc < NC; ++cc) { e[cc] = __expf(lg[tid][cc] - mx); ssum += e[cc]; }
        const float inv = 1.f / ssum;
        float* op = out + (size_t)(r0 + tid) * NC;
        #pragma unroll
        for (int cc = 0; cc < NC; ++cc) op[cc] = e[cc] * inv;
    }
}

extern "C" void kernel_launch(void* const* d_in, const int* in_sizes, int n_in,
                              void* d_out, int out_size, void* d_ws, size_t ws_size,
                              hipStream_t stream) {
    const float* x     = (const float*)d_in[0];
    const float* W_ih  = (const float*)d_in[1];
    const float* W_hh  = (const float*)d_in[2];
    const float* b_ih  = (const float*)d_in[3];
    const float* b_hh  = (const float*)d_in[4];
    const float* W_out = (const float*)d_in[5];
    const float* b_out = (const float*)d_in[6];
    (void)in_sizes; (void)n_in; (void)d_ws; (void)ws_size; (void)out_size;

    gru_mfma<<<BB / ROWS, NTHREADS, 0, stream>>>(x, W_ih, W_hh, b_ih, b_hh,
                                                 W_out, b_out, (float*)d_out);
}